// Round 4
// baseline (318.613 us; speedup 1.0000x reference)
//
#include <hip/hip_runtime.h>
#include <math.h>

typedef unsigned int u32;
typedef _Float16 f16x8 __attribute__((ext_vector_type(8)));
typedef _Float16 f16x4 __attribute__((ext_vector_type(4)));
typedef float f32x4 __attribute__((ext_vector_type(4)));
typedef __attribute__((address_space(1))) const char gch;
typedef __attribute__((address_space(3))) char lch;

#define ZD 256      // z_dim (C)
#define KC 1024     // number of codes
#define TT 4096     // T
#define BB 16       // B
#define NROWS (BB*TT)     // 65536
#define TAU 0.08f         // margin threshold for exact-fp32 rescore (2-term split)
#define FLAGCAP 32768

// ---------------- prep: re=||e||^2, emb->fp16 hi, zero hist/cnt/scal ----------------
__global__ __launch_bounds__(256)
void vq_prep_kernel(const float* __restrict__ emb, _Float16* __restrict__ eh,
                    float* __restrict__ re, float* __restrict__ hist,
                    int* __restrict__ cnt, float* __restrict__ scal) {
    int gid  = blockIdx.x * 256 + threadIdx.x;
    if (gid < KC) hist[gid] = 0.f;
    if (gid < 4)  scal[gid] = 0.f;
    if (gid == 0) cnt[0] = 0;

    int code = gid >> 6;   // one wave per code
    int lane = threadIdx.x & 63;
    float4 v = *(const float4*)(emb + (size_t)code * ZD + lane * 4);
    float s = v.x*v.x + v.y*v.y + v.z*v.z + v.w*v.w;
    #pragma unroll
    for (int off = 32; off; off >>= 1) s += __shfl_down(s, off, 64);
    if (lane == 0) re[code] = s;

    f16x4 hv;
    hv[0] = (_Float16)v.x; hv[1] = (_Float16)v.y;
    hv[2] = (_Float16)v.z; hv[3] = (_Float16)v.w;
    *(f16x4*)(eh + (size_t)code * ZD + lane * 4) = hv;
}

// ---- stage one 32-code hi tile (16KB) via global_load_lds, swizzled source ----
__device__ __forceinline__ void stage_tile(const char* ehc, char* dstbase,
                                           int tile, int w, int l) {
    const int srow = tile * 16384;          // 32 codes * 512B
    #pragma unroll
    for (int j = 0; j < 4; ++j) {
        const int gi  = w * 4 + j;          // 0..15
        const int c   = 2 * gi + (l >> 5);  // local code this lane's 16B lands in
        const int kbs = (l & 31) * 16;      // byte offset within code row
        const int off = srow + c * 512 + (kbs ^ ((c & 7) << 4));
        __builtin_amdgcn_global_load_lds((gch*)(ehc + off),
                                         (lch*)(dstbase + gi * 1024), 16, 0, 0);
    }
}

// ---------------- main argmin via fp16 2-term MFMA, e-hi staged in LDS ----------------
// 512 blocks x 256 threads. Block: 128 rows; wave w: rows [32w,32w+32).
// Code loop: 32 tiles x 32 codes, double-buffered LDS, 1 barrier/tile.
__global__ __launch_bounds__(256, 2)
void vq_argmin_mfma(const float* __restrict__ z, const _Float16* __restrict__ eh,
                    const float* __restrict__ re, int* __restrict__ idx,
                    int* __restrict__ cnt, int* __restrict__ flags) {
    __shared__ __align__(16) char lds[36864];   // 2 x 16KB e-buf + 4KB re

    const int tid = threadIdx.x;
    const int w   = tid >> 6;
    const int l   = tid & 63;
    const int lane15 = l & 15;
    const int lk     = l >> 4;
    const int r0  = blockIdx.x * 128;
    const int b   = r0 >> 12;
    const int t0  = r0 & 4095;
    const char* ehc = (const char*)eh;

    // re -> LDS (4KB)
    float* reL = (float*)(lds + 32768);
    *(float4*)(reL + tid * 4) = *(const float4*)(re + tid * 4);

    // z A-fragments direct from global, fp16 hi/lo split, kept in registers
    f16x8 ah[2][8], al[2][8];
    {
        const float* zw = z + (size_t)b * ZD * TT + t0 + w * 32;
        #pragma unroll
        for (int rg = 0; rg < 2; ++rg) {
            const float* zr = zw + rg * 16 + lane15;
            #pragma unroll
            for (int ks = 0; ks < 8; ++ks) {
                const int kb = ks * 32 + lk * 8;
                f16x8 h, lo;
                #pragma unroll
                for (int j = 0; j < 8; ++j) {
                    float v = zr[(size_t)(kb + j) * TT];
                    _Float16 hh = (_Float16)v;
                    h[j]  = hh;
                    lo[j] = (_Float16)(v - (float)hh);
                }
                ah[rg][ks] = h; al[rg][ks] = lo;
            }
        }
    }

    float v1[8], v2[8];
    int   i1[8];
    #pragma unroll
    for (int s8 = 0; s8 < 8; ++s8) { v1[s8] = 3.4e38f; v2[s8] = 3.4e38f; i1[s8] = 0; }

    __syncthreads();                 // reL visible; clean vmem counter state
    stage_tile(ehc, lds, 0, w, l);

    for (int t = 0; t < 32; ++t) {
        const int cur = t & 1;
        asm volatile("s_waitcnt vmcnt(0)" ::: "memory");   // stage(t) landed
        __builtin_amdgcn_sched_barrier(0);
        __builtin_amdgcn_s_barrier();                      // all waves staged & done reading buf[cur^1]
        if (t < 31) stage_tile(ehc, lds + ((cur ^ 1) << 14), t + 1, w, l);

        const char* hb = lds + (cur << 14);
        #pragma unroll
        for (int cg = 0; cg < 2; ++cg) {
            const int c  = cg * 16 + lane15;        // local code
            const int sw = (c & 7) << 4;
            f16x8 bh[8];
            #pragma unroll
            for (int ks = 0; ks < 8; ++ks)
                bh[ks] = *(const f16x8*)(hb + c * 512 + ((lk * 16 + ks * 64) ^ sw));

            f32x4 a0h = {0,0,0,0}, a0l = {0,0,0,0};
            f32x4 a1h = {0,0,0,0}, a1l = {0,0,0,0};
            __builtin_amdgcn_s_setprio(1);
            #pragma unroll
            for (int ks = 0; ks < 8; ++ks) {
                a0h = __builtin_amdgcn_mfma_f32_16x16x32_f16(ah[0][ks], bh[ks], a0h, 0, 0, 0);
                a1h = __builtin_amdgcn_mfma_f32_16x16x32_f16(ah[1][ks], bh[ks], a1h, 0, 0, 0);
                a0l = __builtin_amdgcn_mfma_f32_16x16x32_f16(al[0][ks], bh[ks], a0l, 0, 0, 0);
                a1l = __builtin_amdgcn_mfma_f32_16x16x32_f16(al[1][ks], bh[ks], a1l, 0, 0, 0);
            }
            __builtin_amdgcn_s_setprio(0);

            const int codeg = t * 32 + cg * 16 + lane15;
            const float rc = reL[codeg];
            #pragma unroll
            for (int r = 0; r < 4; ++r) {
                float s0 = fmaf(-2.f, a0h[r] + a0l[r], rc);
                if (s0 < v1[r]) { v2[r] = v1[r]; v1[r] = s0; i1[r] = codeg; }
                else if (s0 < v2[r]) v2[r] = s0;
                float s1 = fmaf(-2.f, a1h[r] + a1l[r], rc);
                if (s1 < v1[4 + r]) { v2[4 + r] = v1[4 + r]; v1[4 + r] = s1; i1[4 + r] = codeg; }
                else if (s1 < v2[4 + r]) v2[4 + r] = s1;
            }
        }
    }

    // reduce across the 16 lanes holding different codes (same rows)
    #pragma unroll
    for (int off = 1; off < 16; off <<= 1) {
        #pragma unroll
        for (int s8 = 0; s8 < 8; ++s8) {
            float ov1 = __shfl_xor(v1[s8], off, 64);
            int   oi1 = __shfl_xor(i1[s8], off, 64);
            float ov2 = __shfl_xor(v2[s8], off, 64);
            float nv2 = fminf(fmaxf(v1[s8], ov1), fminf(v2[s8], ov2));
            if (ov1 < v1[s8] || (ov1 == v1[s8] && oi1 < i1[s8])) { v1[s8] = ov1; i1[s8] = oi1; }
            v2[s8] = nv2;
        }
    }
    if (lane15 == 0) {
        #pragma unroll
        for (int s8 = 0; s8 < 8; ++s8) {
            const int rg = s8 >> 2, rr = s8 & 3;
            const int row = r0 + w * 32 + rg * 16 + lk * 4 + rr;
            idx[row] = i1[s8];
            if (v2[s8] - v1[s8] < TAU) {
                int p = atomicAdd(cnt, 1);
                if (p < FLAGCAP) flags[p] = row;
            }
        }
    }
}

// ---------------- exact fp32 rescore for flagged (near-tie) rows ----------------
__global__ __launch_bounds__(256)
void vq_fixup_kernel(const float* __restrict__ z, const float* __restrict__ emb,
                     const float* __restrict__ re, const int* __restrict__ cnt,
                     const int* __restrict__ flags, int* __restrict__ idx) {
    __shared__ float zrow[ZD];
    __shared__ float rv[256];
    __shared__ int   ri[256];
    const int tid = threadIdx.x;
    int n = *cnt;
    if (n > FLAGCAP) n = FLAGCAP;
    for (int f = blockIdx.x; f < n; f += gridDim.x) {
        int r = flags[f];
        int b = r >> 12, t = r & 4095;
        __syncthreads();
        zrow[tid] = z[(size_t)b * ZD * TT + (size_t)tid * TT + t];
        __syncthreads();
        float best = 3.4e38f; int bi = 0;
        for (int c = tid; c < KC; c += 256) {
            const float* ec = emb + (size_t)c * ZD;
            float s = 0.f;
            #pragma unroll 8
            for (int k = 0; k < ZD; ++k) s = fmaf(zrow[k], ec[k], s);
            float d = fmaf(-2.0f, s, re[c]);
            if (d < best || (d == best && c < bi)) { best = d; bi = c; }
        }
        rv[tid] = best; ri[tid] = bi;
        __syncthreads();
        for (int st = 128; st; st >>= 1) {
            if (tid < st) {
                float ov = rv[tid + st]; int oi = ri[tid + st];
                if (ov < rv[tid] || (ov == rv[tid] && oi < ri[tid])) { rv[tid] = ov; ri[tid] = oi; }
            }
            __syncthreads();
        }
        if (tid == 0) idx[r] = ri[0];
        __syncthreads();
    }
}

// ---------------- scatter z_vq to (B,C,T) + losses + histogram ----------------
__global__ __launch_bounds__(256)
void vq_scatter_kernel(const float* __restrict__ z, const float* __restrict__ emb,
                       const int* __restrict__ idx, float* __restrict__ out,
                       float* __restrict__ scal, float* __restrict__ hist) {
    const int b   = blockIdx.x >> 4;
    const int tch = blockIdx.x & 15;
    const int t   = (tch << 8) + threadIdx.x;
    const int row = (b << 12) + t;
    const int ii  = idx[row];
    const float4* er = (const float4*)(emb + (size_t)ii * ZD);
    const size_t base = ((size_t)b << 20) + (size_t)t;   // b*C*T + t

    atomicAdd(&hist[ii], 1.0f);

    float lsum = 0.f;
    #pragma unroll 4
    for (int c4 = 0; c4 < ZD / 4; ++c4) {
        float4 ev = er[c4];
        size_t a0 = base + ((size_t)c4 << 14);           // (4*c4)*4096
        float d;
        d = ev.x - z[a0];            out[a0]          = ev.x; lsum = fmaf(d, d, lsum);
        d = ev.y - z[a0 + 4096];     out[a0 + 4096]   = ev.y; lsum = fmaf(d, d, lsum);
        d = ev.z - z[a0 + 8192];     out[a0 + 8192]   = ev.z; lsum = fmaf(d, d, lsum);
        d = ev.w - z[a0 + 12288];    out[a0 + 12288]  = ev.w; lsum = fmaf(d, d, lsum);
    }
    #pragma unroll
    for (int off = 32; off; off >>= 1) lsum += __shfl_down(lsum, off, 64);
    __shared__ float wred[4];
    if ((threadIdx.x & 63) == 0) wred[threadIdx.x >> 6] = lsum;
    __syncthreads();
    if (threadIdx.x == 0) {
        float tt = wred[0] + wred[1] + wred[2] + wred[3];
        atomicAdd(scal + 0, tt);   // z_qut_loss
        atomicAdd(scal + 1, tt);   // z_enc_loss (same forward value)
    }
}

// ---------------- perplexity ----------------
__global__ __launch_bounds__(256)
void vq_perplexity_kernel(const float* __restrict__ hist, float* __restrict__ outp) {
    __shared__ float red[256];
    float s = 0.f;
    for (int j = threadIdx.x; j < KC; j += 256) {
        float p = hist[j] * (1.0f / (float)NROWS);
        s -= p * logf(p + 1e-10f);
    }
    red[threadIdx.x] = s;
    __syncthreads();
    for (int st = 128; st > 0; st >>= 1) {
        if (threadIdx.x < st) red[threadIdx.x] += red[threadIdx.x + st];
        __syncthreads();
    }
    if (threadIdx.x == 0) outp[0] = expf(red[0]);
}

// ---------------- sparsity: mean(logsumexp(E E^T row) - diag), 8 rows/block ----------------
__global__ __launch_bounds__(256)
void vq_sparsity_kernel(const float* __restrict__ emb, float* __restrict__ outp) {
    const int tid = threadIdx.x;
    const int r0  = blockIdx.x * 8;       // 128 blocks
    __shared__ __align__(16) float er[8][260];
    __shared__ float red[256];
    __shared__ float shD[8];

    for (int i = tid; i < 8 * 256; i += 256) er[i >> 8][i & 255] = emb[(size_t)r0 * ZD + i];
    __syncthreads();

    float dots[4][8];
    #pragma unroll
    for (int cc = 0; cc < 4; ++cc) {
        int c = cc * 256 + tid;
        const float4* ec = (const float4*)(emb + (size_t)c * ZD);
        float a[8];
        #pragma unroll
        for (int r = 0; r < 8; ++r) a[r] = 0.f;
        for (int k4 = 0; k4 < ZD / 4; ++k4) {
            float4 e4 = ec[k4];
            #pragma unroll
            for (int r = 0; r < 8; ++r) {
                float4 a4 = *(const float4*)&er[r][k4 * 4];
                a[r] = fmaf(e4.x, a4.x, a[r]);
                a[r] = fmaf(e4.y, a4.y, a[r]);
                a[r] = fmaf(e4.z, a4.z, a[r]);
                a[r] = fmaf(e4.w, a4.w, a[r]);
            }
        }
        #pragma unroll
        for (int r = 0; r < 8; ++r) dots[cc][r] = a[r];
        int gr = c - r0;
        if (gr >= 0 && gr < 8) shD[gr] = a[gr];   // diag element
    }

    float acc = 0.f;
    for (int r = 0; r < 8; ++r) {
        float m = fmaxf(fmaxf(dots[0][r], dots[1][r]), fmaxf(dots[2][r], dots[3][r]));
        __syncthreads();
        red[tid] = m;
        __syncthreads();
        for (int st = 128; st > 0; st >>= 1) {
            if (tid < st) red[tid] = fmaxf(red[tid], red[tid + st]);
            __syncthreads();
        }
        float M = red[0];
        __syncthreads();
        float s = expf(dots[0][r] - M) + expf(dots[1][r] - M)
                + expf(dots[2][r] - M) + expf(dots[3][r] - M);
        red[tid] = s;
        __syncthreads();
        for (int st = 128; st > 0; st >>= 1) {
            if (tid < st) red[tid] += red[tid + st];
            __syncthreads();
        }
        if (tid == 0) acc += M + logf(red[0]) - shD[r];
        __syncthreads();
    }
    if (tid == 0) atomicAdd(outp, acc * (1.0f / (float)KC));
}

extern "C" void kernel_launch(void* const* d_in, const int* in_sizes, int n_in,
                              void* d_out, int out_size, void* d_ws, size_t ws_size,
                              hipStream_t stream) {
    const float* z   = (const float*)d_in[0];
    const float* emb = (const float*)d_in[1];
    float* out = (float*)d_out;
    const size_t NOUT = (size_t)BB * ZD * TT;    // 16777216
    float* scal = out + NOUT;                    // [qut, enc, perp, sparsity]

    float* re    = (float*)d_ws;                 // 1024 f32
    float* hist  = re + KC;                      // 1024 f32
    int*   idx   = (int*)(hist + KC);            // 65536 i32
    int*   cnt   = idx + NROWS;                  // 4 i32 (16B)
    int*   flags = cnt + 4;                      // FLAGCAP i32
    _Float16* eh = (_Float16*)(flags + FLAGCAP); // 1024*256 f16

    vq_prep_kernel<<<KC / 4, 256, 0, stream>>>(emb, eh, re, hist, cnt, scal);
    vq_argmin_mfma<<<NROWS / 128, 256, 0, stream>>>(z, eh, re, idx, cnt, flags);
    vq_fixup_kernel<<<512, 256, 0, stream>>>(z, emb, re, cnt, flags, idx);
    vq_sparsity_kernel<<<KC / 8, 256, 0, stream>>>(emb, scal + 3);
    vq_scatter_kernel<<<(BB * TT) / 256, 256, 0, stream>>>(z, emb, idx, out, scal, hist);
    vq_perplexity_kernel<<<1, 256, 0, stream>>>(hist, scal + 2);
}

// Round 5
// 274.236 us; speedup vs baseline: 1.1618x; 1.1618x over previous
//
#include <hip/hip_runtime.h>
#include <math.h>

typedef unsigned int u32;
typedef _Float16 f16x8 __attribute__((ext_vector_type(8)));
typedef _Float16 f16x4 __attribute__((ext_vector_type(4)));
typedef float f32x4 __attribute__((ext_vector_type(4)));
typedef __attribute__((address_space(1))) const char gch;
typedef __attribute__((address_space(3))) char lch;

#define ZD 256      // z_dim (C)
#define KC 1024     // number of codes
#define TT 4096     // T
#define BB 16       // B
#define NROWS (BB*TT)     // 65536
#define TAU 0.08f         // margin threshold (single-term fp16: ~9 sigma)
#define FLAGCAP 32768

// ---------------- prep: re=||e||^2, emb->fp16, zero hist/cnt/scal ----------------
__global__ __launch_bounds__(256)
void vq_prep_kernel(const float* __restrict__ emb, _Float16* __restrict__ eh,
                    float* __restrict__ re, float* __restrict__ hist,
                    int* __restrict__ cnt, float* __restrict__ scal) {
    int gid  = blockIdx.x * 256 + threadIdx.x;
    if (gid < KC) hist[gid] = 0.f;
    if (gid < 4)  scal[gid] = 0.f;
    if (gid == 0) cnt[0] = 0;

    int code = gid >> 6;   // one wave per code
    int lane = threadIdx.x & 63;
    float4 v = *(const float4*)(emb + (size_t)code * ZD + lane * 4);
    float s = v.x*v.x + v.y*v.y + v.z*v.z + v.w*v.w;
    #pragma unroll
    for (int off = 32; off; off >>= 1) s += __shfl_down(s, off, 64);
    if (lane == 0) re[code] = s;

    f16x4 hv;
    hv[0] = (_Float16)v.x; hv[1] = (_Float16)v.y;
    hv[2] = (_Float16)v.z; hv[3] = (_Float16)v.w;
    *(f16x4*)(eh + (size_t)code * ZD + lane * 4) = hv;
}

// ---- stage one 64-code tile (32KB) via global_load_lds, pre-swizzled source ----
__device__ __forceinline__ void stage_tile(const char* ehc, char* dstbase,
                                           int tile, int w, int l) {
    const int srow = tile * 32768;          // 64 codes * 512B
    #pragma unroll
    for (int j = 0; j < 8; ++j) {
        const int gi  = w * 8 + j;          // 0..31
        const int c   = 2 * gi + (l >> 5);  // local code this lane's 16B lands in
        const int kbs = (l & 31) * 16;      // byte offset within code row
        const int off = srow + c * 512 + (kbs ^ ((c & 7) << 4));
        __builtin_amdgcn_global_load_lds((gch*)(ehc + off),
                                         (lch*)(dstbase + gi * 1024), 16, 0, 0);
    }
}

// ---------------- main argmin via single-term fp16 MFMA, e staged in LDS ----------------
// 512 blocks x 256 threads. Block: 128 rows; wave w: rows [32w,32w+32).
// Code loop: 16 tiles x 64 codes, double-buffered LDS, 1 barrier/tile.
__global__ __launch_bounds__(256, 2)
void vq_argmin_mfma(const float* __restrict__ z, const _Float16* __restrict__ eh,
                    const float* __restrict__ re, int* __restrict__ idx,
                    int* __restrict__ cnt, int* __restrict__ flags) {
    __shared__ __align__(16) char lds[69632];   // 2 x 32KB e-buf + 4KB re

    const int tid = threadIdx.x;
    const int w   = tid >> 6;
    const int l   = tid & 63;
    const int lane15 = l & 15;
    const int lk     = l >> 4;
    const int r0  = blockIdx.x * 128;
    const int b   = r0 >> 12;
    const int t0  = r0 & 4095;
    const char* ehc = (const char*)eh;

    // re -> LDS (4KB)
    float* reL = (float*)(lds + 65536);
    *(float4*)(reL + tid * 4) = *(const float4*)(re + tid * 4);

    // z A-fragments direct from global, fp16, kept in registers (64 VGPR)
    f16x8 ah[2][8];
    {
        const float* zw = z + (size_t)b * ZD * TT + t0 + w * 32;
        #pragma unroll
        for (int rg = 0; rg < 2; ++rg) {
            const float* zr = zw + rg * 16 + lane15;
            #pragma unroll
            for (int ks = 0; ks < 8; ++ks) {
                const int kb = ks * 32 + lk * 8;
                f16x8 h;
                #pragma unroll
                for (int j = 0; j < 8; ++j) h[j] = (_Float16)zr[(size_t)(kb + j) * TT];
                ah[rg][ks] = h;
            }
        }
    }

    float v1[8], v2[8];
    int   i1[8];
    #pragma unroll
    for (int s8 = 0; s8 < 8; ++s8) { v1[s8] = 3.4e38f; v2[s8] = 3.4e38f; i1[s8] = 0; }

    // drain this wave's z loads + reL ds_write so counted vmcnt sees only stages
    asm volatile("s_waitcnt vmcnt(0) lgkmcnt(0)" ::: "memory");
    stage_tile(ehc, lds, 0, w, l);

    for (int t = 0; t < 16; ++t) {
        const int cur = t & 1;
        asm volatile("s_waitcnt vmcnt(0)" ::: "memory");   // stage(t) landed
        __builtin_amdgcn_sched_barrier(0);
        __builtin_amdgcn_s_barrier();   // all waves: staged, done reading buf[cur^1]
        if (t < 15) stage_tile(ehc, lds + ((cur ^ 1) << 15), t + 1, w, l);

        const char* hb = lds + (cur << 15);
        #pragma unroll
        for (int cg = 0; cg < 4; ++cg) {
            const int c  = cg * 16 + lane15;        // local code 0..63
            const int sw = (c & 7) << 4;
            f16x8 bh[8];
            #pragma unroll
            for (int ks = 0; ks < 8; ++ks)
                bh[ks] = *(const f16x8*)(hb + c * 512 + ((lk * 16 + ks * 64) ^ sw));

            f32x4 a0 = {0,0,0,0};
            f32x4 a1 = {0,0,0,0};
            __builtin_amdgcn_s_setprio(1);
            #pragma unroll
            for (int ks = 0; ks < 8; ++ks) {
                a0 = __builtin_amdgcn_mfma_f32_16x16x32_f16(ah[0][ks], bh[ks], a0, 0, 0, 0);
                a1 = __builtin_amdgcn_mfma_f32_16x16x32_f16(ah[1][ks], bh[ks], a1, 0, 0, 0);
            }
            __builtin_amdgcn_s_setprio(0);

            const int codeg = t * 64 + cg * 16 + lane15;
            const float rc = reL[codeg];
            #pragma unroll
            for (int r = 0; r < 4; ++r) {
                float s0 = fmaf(-2.f, a0[r], rc);
                if (s0 < v1[r]) { v2[r] = v1[r]; v1[r] = s0; i1[r] = codeg; }
                else if (s0 < v2[r]) v2[r] = s0;
                float s1 = fmaf(-2.f, a1[r], rc);
                if (s1 < v1[4 + r]) { v2[4 + r] = v1[4 + r]; v1[4 + r] = s1; i1[4 + r] = codeg; }
                else if (s1 < v2[4 + r]) v2[4 + r] = s1;
            }
        }
    }

    // reduce across the 16 lanes holding different codes (same rows)
    #pragma unroll
    for (int off = 1; off < 16; off <<= 1) {
        #pragma unroll
        for (int s8 = 0; s8 < 8; ++s8) {
            float ov1 = __shfl_xor(v1[s8], off, 64);
            int   oi1 = __shfl_xor(i1[s8], off, 64);
            float ov2 = __shfl_xor(v2[s8], off, 64);
            float nv2 = fminf(fmaxf(v1[s8], ov1), fminf(v2[s8], ov2));
            if (ov1 < v1[s8] || (ov1 == v1[s8] && oi1 < i1[s8])) { v1[s8] = ov1; i1[s8] = oi1; }
            v2[s8] = nv2;
        }
    }
    if (lane15 == 0) {
        #pragma unroll
        for (int s8 = 0; s8 < 8; ++s8) {
            const int rg = s8 >> 2, rr = s8 & 3;
            const int row = r0 + w * 32 + rg * 16 + lk * 4 + rr;
            idx[row] = i1[s8];
            if (v2[s8] - v1[s8] < TAU) {
                int p = atomicAdd(cnt, 1);
                if (p < FLAGCAP) flags[p] = row;
            }
        }
    }
}

// ---------------- exact fp32 rescore for flagged (near-tie) rows ----------------
__global__ __launch_bounds__(256)
void vq_fixup_kernel(const float* __restrict__ z, const float* __restrict__ emb,
                     const float* __restrict__ re, const int* __restrict__ cnt,
                     const int* __restrict__ flags, int* __restrict__ idx) {
    __shared__ float zrow[ZD];
    __shared__ float rv[256];
    __shared__ int   ri[256];
    const int tid = threadIdx.x;
    int n = *cnt;
    if (n > FLAGCAP) n = FLAGCAP;
    for (int f = blockIdx.x; f < n; f += gridDim.x) {
        int r = flags[f];
        int b = r >> 12, t = r & 4095;
        __syncthreads();
        zrow[tid] = z[(size_t)b * ZD * TT + (size_t)tid * TT + t];
        __syncthreads();
        float best = 3.4e38f; int bi = 0;
        for (int c = tid; c < KC; c += 256) {
            const float* ec = emb + (size_t)c * ZD;
            float s = 0.f;
            #pragma unroll 8
            for (int k = 0; k < ZD; ++k) s = fmaf(zrow[k], ec[k], s);
            float d = fmaf(-2.0f, s, re[c]);
            if (d < best || (d == best && c < bi)) { best = d; bi = c; }
        }
        rv[tid] = best; ri[tid] = bi;
        __syncthreads();
        for (int st = 128; st; st >>= 1) {
            if (tid < st) {
                float ov = rv[tid + st]; int oi = ri[tid + st];
                if (ov < rv[tid] || (ov == rv[tid] && oi < ri[tid])) { rv[tid] = ov; ri[tid] = oi; }
            }
            __syncthreads();
        }
        if (tid == 0) idx[r] = ri[0];
        __syncthreads();
    }
}

// ---------------- scatter z_vq to (B,C,T) + losses + histogram ----------------
__global__ __launch_bounds__(256)
void vq_scatter_kernel(const float* __restrict__ z, const float* __restrict__ emb,
                       const int* __restrict__ idx, float* __restrict__ out,
                       float* __restrict__ scal, float* __restrict__ hist) {
    const int b   = blockIdx.x >> 4;
    const int tch = blockIdx.x & 15;
    const int t   = (tch << 8) + threadIdx.x;
    const int row = (b << 12) + t;
    const int ii  = idx[row];
    const float4* er = (const float4*)(emb + (size_t)ii * ZD);
    const size_t base = ((size_t)b << 20) + (size_t)t;   // b*C*T + t

    atomicAdd(&hist[ii], 1.0f);

    float lsum = 0.f;
    #pragma unroll 4
    for (int c4 = 0; c4 < ZD / 4; ++c4) {
        float4 ev = er[c4];
        size_t a0 = base + ((size_t)c4 << 14);           // (4*c4)*4096
        float d;
        d = ev.x - z[a0];            out[a0]          = ev.x; lsum = fmaf(d, d, lsum);
        d = ev.y - z[a0 + 4096];     out[a0 + 4096]   = ev.y; lsum = fmaf(d, d, lsum);
        d = ev.z - z[a0 + 8192];     out[a0 + 8192]   = ev.z; lsum = fmaf(d, d, lsum);
        d = ev.w - z[a0 + 12288];    out[a0 + 12288]  = ev.w; lsum = fmaf(d, d, lsum);
    }
    #pragma unroll
    for (int off = 32; off; off >>= 1) lsum += __shfl_down(lsum, off, 64);
    __shared__ float wred[4];
    if ((threadIdx.x & 63) == 0) wred[threadIdx.x >> 6] = lsum;
    __syncthreads();
    if (threadIdx.x == 0) {
        float tt = wred[0] + wred[1] + wred[2] + wred[3];
        atomicAdd(scal + 0, tt);   // z_qut_loss
        atomicAdd(scal + 1, tt);   // z_enc_loss (same forward value)
    }
}

// ---------------- perplexity ----------------
__global__ __launch_bounds__(256)
void vq_perplexity_kernel(const float* __restrict__ hist, float* __restrict__ outp) {
    __shared__ float red[256];
    float s = 0.f;
    for (int j = threadIdx.x; j < KC; j += 256) {
        float p = hist[j] * (1.0f / (float)NROWS);
        s -= p * logf(p + 1e-10f);
    }
    red[threadIdx.x] = s;
    __syncthreads();
    for (int st = 128; st > 0; st >>= 1) {
        if (threadIdx.x < st) red[threadIdx.x] += red[threadIdx.x + st];
        __syncthreads();
    }
    if (threadIdx.x == 0) outp[0] = expf(red[0]);
}

// ---------------- sparsity: mean(logsumexp(E E^T row) - diag), 4 rows/block ----------------
__global__ __launch_bounds__(256)
void vq_sparsity_kernel(const float* __restrict__ emb, float* __restrict__ outp) {
    const int tid  = threadIdx.x;
    const int w    = tid >> 6;
    const int lane = tid & 63;
    const int r0   = blockIdx.x * 4;       // 256 blocks
    __shared__ __align__(16) float er[4][260];
    __shared__ float wmax[4][4];
    __shared__ float wsum[4][4];
    __shared__ float shD[4];

    for (int i = tid; i < 4 * 256; i += 256) er[i >> 8][i & 255] = emb[(size_t)r0 * ZD + i];
    __syncthreads();

    float dots[4][4];   // [cc][r]
    #pragma unroll
    for (int cc = 0; cc < 4; ++cc) {
        const int c = cc * 256 + tid;
        const float4* ec = (const float4*)(emb + (size_t)c * ZD);
        float a[4] = {0.f, 0.f, 0.f, 0.f};
        #pragma unroll 2
        for (int k16 = 0; k16 < 16; ++k16) {
            float4 e0 = ec[k16 * 4 + 0];
            float4 e1 = ec[k16 * 4 + 1];
            float4 e2 = ec[k16 * 4 + 2];
            float4 e3 = ec[k16 * 4 + 3];
            #pragma unroll
            for (int r = 0; r < 4; ++r) {
                const float* a4 = &er[r][k16 * 16];
                float s = 0.f;
                s = fmaf(e0.x, a4[0],  s); s = fmaf(e0.y, a4[1],  s);
                s = fmaf(e0.z, a4[2],  s); s = fmaf(e0.w, a4[3],  s);
                s = fmaf(e1.x, a4[4],  s); s = fmaf(e1.y, a4[5],  s);
                s = fmaf(e1.z, a4[6],  s); s = fmaf(e1.w, a4[7],  s);
                s = fmaf(e2.x, a4[8],  s); s = fmaf(e2.y, a4[9],  s);
                s = fmaf(e2.z, a4[10], s); s = fmaf(e2.w, a4[11], s);
                s = fmaf(e3.x, a4[12], s); s = fmaf(e3.y, a4[13], s);
                s = fmaf(e3.z, a4[14], s); s = fmaf(e3.w, a4[15], s);
                a[r] += s;
            }
        }
        #pragma unroll
        for (int r = 0; r < 4; ++r) dots[cc][r] = a[r];
        const int gr = c - r0;
        if (gr >= 0 && gr < 4) shD[gr] = a[gr];   // diag element
    }

    #pragma unroll
    for (int r = 0; r < 4; ++r) {
        float m = fmaxf(fmaxf(dots[0][r], dots[1][r]), fmaxf(dots[2][r], dots[3][r]));
        #pragma unroll
        for (int off = 32; off; off >>= 1) m = fmaxf(m, __shfl_xor(m, off, 64));
        if (lane == 0) wmax[r][w] = m;
    }
    __syncthreads();
    #pragma unroll
    for (int r = 0; r < 4; ++r) {
        const float M = fmaxf(fmaxf(wmax[r][0], wmax[r][1]), fmaxf(wmax[r][2], wmax[r][3]));
        float se = expf(dots[0][r] - M) + expf(dots[1][r] - M)
                 + expf(dots[2][r] - M) + expf(dots[3][r] - M);
        #pragma unroll
        for (int off = 32; off; off >>= 1) se += __shfl_xor(se, off, 64);
        if (lane == 0) wsum[r][w] = se;
    }
    __syncthreads();
    if (tid == 0) {
        float acc = 0.f;
        #pragma unroll
        for (int r = 0; r < 4; ++r) {
            const float M = fmaxf(fmaxf(wmax[r][0], wmax[r][1]), fmaxf(wmax[r][2], wmax[r][3]));
            const float S = wsum[r][0] + wsum[r][1] + wsum[r][2] + wsum[r][3];
            acc += M + logf(S) - shD[r];
        }
        atomicAdd(outp, acc * (1.0f / (float)KC));
    }
}

extern "C" void kernel_launch(void* const* d_in, const int* in_sizes, int n_in,
                              void* d_out, int out_size, void* d_ws, size_t ws_size,
                              hipStream_t stream) {
    const float* z   = (const float*)d_in[0];
    const float* emb = (const float*)d_in[1];
    float* out = (float*)d_out;
    const size_t NOUT = (size_t)BB * ZD * TT;    // 16777216
    float* scal = out + NOUT;                    // [qut, enc, perp, sparsity]

    float* re    = (float*)d_ws;                 // 1024 f32
    float* hist  = re + KC;                      // 1024 f32
    int*   idx   = (int*)(hist + KC);            // 65536 i32
    int*   cnt   = idx + NROWS;                  // 4 i32 (16B)
    int*   flags = cnt + 4;                      // FLAGCAP i32
    _Float16* eh = (_Float16*)(flags + FLAGCAP); // 1024*256 f16

    vq_prep_kernel<<<KC / 4, 256, 0, stream>>>(emb, eh, re, hist, cnt, scal);
    vq_argmin_mfma<<<NROWS / 128, 256, 0, stream>>>(z, eh, re, idx, cnt, flags);
    vq_fixup_kernel<<<512, 256, 0, stream>>>(z, emb, re, cnt, flags, idx);
    vq_sparsity_kernel<<<KC / 4, 256, 0, stream>>>(emb, scal + 3);
    vq_scatter_kernel<<<(BB * TT) / 256, 256, 0, stream>>>(z, emb, idx, out, scal, hist);
    vq_perplexity_kernel<<<1, 256, 0, stream>>>(hist, scal + 2);
}

// Round 6
// 251.475 us; speedup vs baseline: 1.2670x; 1.0905x over previous
//
#include <hip/hip_runtime.h>
#include <math.h>

typedef unsigned int u32;
typedef _Float16 f16x8 __attribute__((ext_vector_type(8)));
typedef _Float16 f16x4 __attribute__((ext_vector_type(4)));
typedef float f32x4 __attribute__((ext_vector_type(4)));
typedef __attribute__((address_space(1))) const char gch;
typedef __attribute__((address_space(3))) char lch;

#define ZD 256      // z_dim (C)
#define KC 1024     // number of codes
#define TT 4096     // T
#define BB 16       // B
#define NROWS (BB*TT)     // 65536
#define TAU 0.12f         // margin threshold (~6 sigma of fp16 pairwise err)
#define FLAGCAP 32768

// ---------------- prep (blocks 0..255) + sparsity partials (blocks 256..511) ----------------
__global__ __launch_bounds__(256)
void vq_prep_sparsity(const float* __restrict__ emb, _Float16* __restrict__ eh,
                      float* __restrict__ re, float* __restrict__ hist,
                      int* __restrict__ cnt, float* __restrict__ scal,
                      float* __restrict__ spar) {
    __shared__ __align__(16) float er[4][260];
    __shared__ float wmax[4][4];
    __shared__ float wsum[4][4];
    __shared__ float shD[4];

    const int tid = threadIdx.x;
    if (blockIdx.x < 256) {
        // ---- prep: zero hist/cnt/scal, re=||e||^2, emb->fp16 ----
        int gid = blockIdx.x * 256 + tid;
        if (gid < KC) hist[gid] = 0.f;
        if (gid < 4)  scal[gid] = 0.f;
        if (gid == 0) cnt[0] = 0;

        int code = gid >> 6;   // one wave per code
        int lane = tid & 63;
        float4 v = *(const float4*)(emb + (size_t)code * ZD + lane * 4);
        float s = v.x*v.x + v.y*v.y + v.z*v.z + v.w*v.w;
        #pragma unroll
        for (int off = 32; off; off >>= 1) s += __shfl_down(s, off, 64);
        if (lane == 0) re[code] = s;

        f16x4 hv;
        hv[0] = (_Float16)v.x; hv[1] = (_Float16)v.y;
        hv[2] = (_Float16)v.z; hv[3] = (_Float16)v.w;
        *(f16x4*)(eh + (size_t)code * ZD + lane * 4) = hv;
        return;
    }

    // ---- sparsity: 4 rows/block, partial to spar[bid2] ----
    const int bid2 = blockIdx.x - 256;
    const int w    = tid >> 6;
    const int lane = tid & 63;
    const int r0   = bid2 * 4;

    for (int i = tid; i < 4 * 256; i += 256) er[i >> 8][i & 255] = emb[(size_t)r0 * ZD + i];
    __syncthreads();

    float dots[4][4];   // [cc][r]
    #pragma unroll
    for (int cc = 0; cc < 4; ++cc) {
        const int c = cc * 256 + tid;
        const float4* ec = (const float4*)(emb + (size_t)c * ZD);
        float a[4] = {0.f, 0.f, 0.f, 0.f};
        #pragma unroll 2
        for (int k16 = 0; k16 < 16; ++k16) {
            float4 e0 = ec[k16 * 4 + 0];
            float4 e1 = ec[k16 * 4 + 1];
            float4 e2 = ec[k16 * 4 + 2];
            float4 e3 = ec[k16 * 4 + 3];
            #pragma unroll
            for (int r = 0; r < 4; ++r) {
                const float* a4 = &er[r][k16 * 16];
                float s = 0.f;
                s = fmaf(e0.x, a4[0],  s); s = fmaf(e0.y, a4[1],  s);
                s = fmaf(e0.z, a4[2],  s); s = fmaf(e0.w, a4[3],  s);
                s = fmaf(e1.x, a4[4],  s); s = fmaf(e1.y, a4[5],  s);
                s = fmaf(e1.z, a4[6],  s); s = fmaf(e1.w, a4[7],  s);
                s = fmaf(e2.x, a4[8],  s); s = fmaf(e2.y, a4[9],  s);
                s = fmaf(e2.z, a4[10], s); s = fmaf(e2.w, a4[11], s);
                s = fmaf(e3.x, a4[12], s); s = fmaf(e3.y, a4[13], s);
                s = fmaf(e3.z, a4[14], s); s = fmaf(e3.w, a4[15], s);
                a[r] += s;
            }
        }
        #pragma unroll
        for (int r = 0; r < 4; ++r) dots[cc][r] = a[r];
        const int gr = c - r0;
        if (gr >= 0 && gr < 4) shD[gr] = a[gr];
    }

    #pragma unroll
    for (int r = 0; r < 4; ++r) {
        float m = fmaxf(fmaxf(dots[0][r], dots[1][r]), fmaxf(dots[2][r], dots[3][r]));
        #pragma unroll
        for (int off = 32; off; off >>= 1) m = fmaxf(m, __shfl_xor(m, off, 64));
        if (lane == 0) wmax[r][w] = m;
    }
    __syncthreads();
    #pragma unroll
    for (int r = 0; r < 4; ++r) {
        const float M = fmaxf(fmaxf(wmax[r][0], wmax[r][1]), fmaxf(wmax[r][2], wmax[r][3]));
        float se = expf(dots[0][r] - M) + expf(dots[1][r] - M)
                 + expf(dots[2][r] - M) + expf(dots[3][r] - M);
        #pragma unroll
        for (int off = 32; off; off >>= 1) se += __shfl_xor(se, off, 64);
        if (lane == 0) wsum[r][w] = se;
    }
    __syncthreads();
    if (tid == 0) {
        float acc = 0.f;
        #pragma unroll
        for (int r = 0; r < 4; ++r) {
            const float M = fmaxf(fmaxf(wmax[r][0], wmax[r][1]), fmaxf(wmax[r][2], wmax[r][3]));
            const float S = wsum[r][0] + wsum[r][1] + wsum[r][2] + wsum[r][3];
            acc += M + logf(S) - shD[r];
        }
        spar[bid2] = acc;
    }
}

// ---- stage one 64-code tile (32KB) via global_load_lds, pre-swizzled source (8 waves) ----
__device__ __forceinline__ void stage_tile8(const char* ehc, char* dstbase,
                                            int tile, int w, int l) {
    const int srow = tile * 32768;          // 64 codes * 512B
    #pragma unroll
    for (int j = 0; j < 4; ++j) {
        const int gi  = w * 4 + j;          // 0..31
        const int c   = 2 * gi + (l >> 5);  // local code this lane's 16B lands in
        const int kbs = (l & 31) * 16;
        const int off = srow + c * 512 + (kbs ^ ((c & 7) << 4));
        __builtin_amdgcn_global_load_lds((gch*)(ehc + off),
                                         (lch*)(dstbase + gi * 1024), 16, 0, 0);
    }
}

// ---------------- fused argmin + out-write + loss + hist ----------------
// 512 blocks x 512 threads (8 waves). Block: 128 rows; wave w: rows [16w,16w+16).
// 16 tiles x 64 codes, double-buffered LDS, 1 barrier/tile, 4 waves/SIMD.
__global__ __launch_bounds__(512, 4)
void vq_argmin_mfma(const float* __restrict__ z, const _Float16* __restrict__ eh,
                    const float* __restrict__ emb, const float* __restrict__ re,
                    float* __restrict__ out, float* __restrict__ scal,
                    float* __restrict__ hist, int* __restrict__ cnt,
                    int* __restrict__ flags) {
    __shared__ __align__(16) char lds[71168];
    float* reL   = (float*)(lds + 65536);   // 1024 f32
    float* zsqL  = (float*)(lds + 69632);   // 128 f32
    int*   idsL  = (int*)  (lds + 70144);   // 128 i32
    float* lossL = (float*)(lds + 70656);   // 128 f32

    const int tid = threadIdx.x;
    const int w   = tid >> 6;       // 0..7
    const int l   = tid & 63;
    const int lane15 = l & 15;
    const int lk     = l >> 4;
    const int r0  = blockIdx.x * 128;
    const int b   = r0 >> 12;
    const int t0  = r0 & 4095;
    const char* ehc = (const char*)eh;

    if (tid < 256) *(float4*)(reL + tid * 4) = *(const float4*)(re + tid * 4);

    // z A-fragments (16 rows/wave): row = lane15, k-quarter = lk; also exact ||z||^2
    f16x8 ah[8];
    float zsq = 0.f;
    {
        const float* zr = z + (size_t)b * ZD * TT + t0 + w * 16 + lane15;
        #pragma unroll
        for (int ks = 0; ks < 8; ++ks) {
            f16x8 h;
            #pragma unroll
            for (int j = 0; j < 8; ++j) {
                float v = zr[(size_t)(ks * 32 + lk * 8 + j) * TT];
                zsq = fmaf(v, v, zsq);
                h[j] = (_Float16)v;
            }
            ah[ks] = h;
        }
    }
    zsq += __shfl_xor(zsq, 16, 64);
    zsq += __shfl_xor(zsq, 32, 64);
    if (l < 16) zsqL[w * 16 + lane15] = zsq;

    float v1[4], v2[4];
    int   i1[4];
    #pragma unroll
    for (int r = 0; r < 4; ++r) { v1[r] = 3.4e38f; v2[r] = 3.4e38f; i1[r] = 0; }

    asm volatile("s_waitcnt vmcnt(0) lgkmcnt(0)" ::: "memory");
    stage_tile8(ehc, lds, 0, w, l);

    for (int t = 0; t < 16; ++t) {
        const int cur = t & 1;
        asm volatile("s_waitcnt vmcnt(0)" ::: "memory");   // stage(t) landed
        __builtin_amdgcn_sched_barrier(0);
        __builtin_amdgcn_s_barrier();   // all staged; all done reading buf[cur^1]
        if (t < 15) stage_tile8(ehc, lds + ((cur ^ 1) << 15), t + 1, w, l);

        const char* hb = lds + (cur << 15);
        #pragma unroll
        for (int cg = 0; cg < 4; ++cg) {
            const int c  = cg * 16 + lane15;        // local code 0..63
            const int sw = (c & 7) << 4;
            f16x8 bh[8];
            #pragma unroll
            for (int ks = 0; ks < 8; ++ks)
                bh[ks] = *(const f16x8*)(hb + c * 512 + ((lk * 16 + ks * 64) ^ sw));

            f32x4 a = {0.f, 0.f, 0.f, 0.f};
            __builtin_amdgcn_s_setprio(1);
            #pragma unroll
            for (int ks = 0; ks < 8; ++ks)
                a = __builtin_amdgcn_mfma_f32_16x16x32_f16(ah[ks], bh[ks], a, 0, 0, 0);
            __builtin_amdgcn_s_setprio(0);

            const int codeg = t * 64 + cg * 16 + lane15;
            const float rc = reL[codeg];
            #pragma unroll
            for (int r = 0; r < 4; ++r) {
                float s0 = fmaf(-2.f, a[r], rc);
                if (s0 < v1[r]) { v2[r] = v1[r]; v1[r] = s0; i1[r] = codeg; }
                else if (s0 < v2[r]) v2[r] = s0;
            }
        }
    }

    // reduce across the 16 lanes holding different codes (same rows)
    #pragma unroll
    for (int off = 1; off < 16; off <<= 1) {
        #pragma unroll
        for (int r = 0; r < 4; ++r) {
            float ov1 = __shfl_xor(v1[r], off, 64);
            int   oi1 = __shfl_xor(i1[r], off, 64);
            float ov2 = __shfl_xor(v2[r], off, 64);
            float nv2 = fminf(fmaxf(v1[r], ov1), fminf(v2[r], ov2));
            if (ov1 < v1[r] || (ov1 == v1[r] && oi1 < i1[r])) { v1[r] = ov1; i1[r] = oi1; }
            v2[r] = nv2;
        }
    }
    if (lane15 == 0) {
        #pragma unroll
        for (int r = 0; r < 4; ++r) {
            const int row = w * 16 + lk * 4 + r;    // local row 0..127
            idsL[row] = i1[r];
            const bool fl = (v2[r] - v1[r] < TAU);
            lossL[row] = fl ? 0.f : (zsqL[row] + v1[r]);
            atomicAdd(&hist[i1[r]], 1.0f);
            if (fl) {
                int p = atomicAdd(cnt, 1);
                if (p < FLAGCAP) flags[p] = (r0 + row) | (i1[r] << 16);
            }
        }
    }
    __syncthreads();

    // block loss reduce (threads 0..127 = waves 0,1)
    if (tid < 128) {
        float lv = lossL[tid];
        #pragma unroll
        for (int off = 32; off; off >>= 1) lv += __shfl_down(lv, off, 64);
        if (l == 0) { atomicAdd(scal + 0, lv); atomicAdd(scal + 1, lv); }
    }

    // out-write: wave w covers c in [32w, 32w+32), all 128 rows
    {
        const int c0 = w * 32;
        float* ob = out + (size_t)b * ZD * TT + t0;
        #pragma unroll
        for (int half = 0; half < 2; ++half) {
            const int tt = half * 64 + l;
            const int ii = idsL[tt];
            const float4* er4 = (const float4*)(emb + (size_t)ii * ZD + c0);
            #pragma unroll
            for (int c4 = 0; c4 < 8; ++c4) {
                float4 ev = er4[c4];
                float* o0 = ob + (size_t)(c0 + c4 * 4) * TT + tt;
                o0[0]      = ev.x;
                o0[TT]     = ev.y;
                o0[2 * TT] = ev.z;
                o0[3 * TT] = ev.w;
            }
        }
    }
}

// ---------------- exact fp32 rescore for flagged rows; patch out/loss/hist ----------------
__global__ __launch_bounds__(256)
void vq_fixup_kernel(const float* __restrict__ z, const float* __restrict__ emb,
                     const float* __restrict__ re, const int* __restrict__ cnt,
                     const int* __restrict__ flags, float* __restrict__ out,
                     float* __restrict__ scal, float* __restrict__ hist) {
    __shared__ float zrow[ZD];
    __shared__ float rv[256];
    __shared__ int   ri[256];
    __shared__ float zsqs;
    const int tid = threadIdx.x;
    int n = *cnt;
    if (n > FLAGCAP) n = FLAGCAP;
    for (int f = blockIdx.x; f < n; f += gridDim.x) {
        const int packed = flags[f];
        const int row = packed & 0xFFFF;
        const int old = (packed >> 16) & 0x3FF;
        const int b = row >> 12, t = row & 4095;
        __syncthreads();
        zrow[tid] = z[(size_t)b * ZD * TT + (size_t)tid * TT + t];
        __syncthreads();
        rv[tid] = zrow[tid] * zrow[tid];
        __syncthreads();
        for (int st = 128; st; st >>= 1) {
            if (tid < st) rv[tid] += rv[tid + st];
            __syncthreads();
        }
        if (tid == 0) zsqs = rv[0];
        __syncthreads();

        float best = 3.4e38f; int bi = 0;
        for (int c = tid; c < KC; c += 256) {
            const float* ec = emb + (size_t)c * ZD;
            float s = 0.f;
            #pragma unroll 8
            for (int k = 0; k < ZD; ++k) s = fmaf(zrow[k], ec[k], s);
            float d = fmaf(-2.0f, s, re[c]);
            if (d < best || (d == best && c < bi)) { best = d; bi = c; }
        }
        rv[tid] = best; ri[tid] = bi;
        __syncthreads();
        for (int st = 128; st; st >>= 1) {
            if (tid < st) {
                float ov = rv[tid + st]; int oi = ri[tid + st];
                if (ov < rv[tid] || (ov == rv[tid] && oi < ri[tid])) { rv[tid] = ov; ri[tid] = oi; }
            }
            __syncthreads();
        }
        const int nw = ri[0];
        if (tid == 0) {
            const float dmin = zsqs + rv[0];
            atomicAdd(scal + 0, dmin);
            atomicAdd(scal + 1, dmin);
            if (nw != old) { atomicAdd(&hist[old], -1.0f); atomicAdd(&hist[nw], 1.0f); }
        }
        if (nw != old)
            out[(size_t)b * ZD * TT + (size_t)tid * TT + t] = emb[(size_t)nw * ZD + tid];
        __syncthreads();
    }
}

// ---------------- final: perplexity from hist + sparsity partial sum ----------------
__global__ __launch_bounds__(256)
void vq_final_kernel(const float* __restrict__ hist, const float* __restrict__ spar,
                     float* __restrict__ scal) {
    __shared__ float red[256];
    const int tid = threadIdx.x;
    float s = 0.f;
    for (int j = tid; j < KC; j += 256) {
        float p = hist[j] * (1.0f / (float)NROWS);
        s -= p * logf(p + 1e-10f);
    }
    red[tid] = s;
    __syncthreads();
    for (int st = 128; st; st >>= 1) {
        if (tid < st) red[tid] += red[tid + st];
        __syncthreads();
    }
    if (tid == 0) scal[2] = expf(red[0]);
    __syncthreads();
    red[tid] = spar[tid];
    __syncthreads();
    for (int st = 128; st; st >>= 1) {
        if (tid < st) red[tid] += red[tid + st];
        __syncthreads();
    }
    if (tid == 0) scal[3] = red[0] * (1.0f / (float)KC);
}

extern "C" void kernel_launch(void* const* d_in, const int* in_sizes, int n_in,
                              void* d_out, int out_size, void* d_ws, size_t ws_size,
                              hipStream_t stream) {
    const float* z   = (const float*)d_in[0];
    const float* emb = (const float*)d_in[1];
    float* out = (float*)d_out;
    const size_t NOUT = (size_t)BB * ZD * TT;    // 16777216
    float* scal = out + NOUT;                    // [qut, enc, perp, sparsity]

    float* re    = (float*)d_ws;                 // 1024 f32
    float* hist  = re + KC;                      // 1024 f32
    int*   cnt   = (int*)(hist + KC);            // 4 i32
    int*   flags = cnt + 4;                      // FLAGCAP i32
    float* spar  = (float*)(flags + FLAGCAP);    // 256 f32
    _Float16* eh = (_Float16*)(spar + 256);      // 1024*256 f16

    vq_prep_sparsity<<<512, 256, 0, stream>>>(emb, eh, re, hist, cnt, scal, spar);
    vq_argmin_mfma<<<NROWS / 128, 512, 0, stream>>>(z, eh, emb, re, out, scal, hist, cnt, flags);
    vq_fixup_kernel<<<512, 256, 0, stream>>>(z, emb, re, cnt, flags, out, scal, hist);
    vq_final_kernel<<<1, 256, 0, stream>>>(hist, spar, scal);
}